// Round 6
// baseline (340.854 us; speedup 1.0000x reference)
//
#include <hip/hip_runtime.h>

typedef unsigned short u16;
typedef unsigned int u32;
typedef __bf16 bf16x8 __attribute__((ext_vector_type(8)));
typedef float f32x4 __attribute__((ext_vector_type(4)));

// ---------- helpers ----------
__device__ __forceinline__ u16 f2bf(float f) {
  union { float f; u32 u; } v; v.f = f;
  u32 r = v.u + 0x7fffu + ((v.u >> 16) & 1u);   // RNE
  return (u16)(r >> 16);
}

__device__ __forceinline__ u32 pack2(float a, float b) {   // 2xbf16 (RNE via native cvt)
  union { __bf16 h[2]; u32 u; } x;
  x.h[0] = (__bf16)a; x.h[1] = (__bf16)b;
  return x.u;
}

__device__ __forceinline__ bf16x8 ldb128(const u16* p) {
  return *reinterpret_cast<const bf16x8*>(p);
}

__device__ __forceinline__ f32x4 mfma16(bf16x8 a, bf16x8 b, f32x4 c) {
  return __builtin_amdgcn_mfma_f32_16x16x32_bf16(a, b, c, 0, 0, 0);
}

typedef const __attribute__((address_space(1))) u32* gas_p;
typedef __attribute__((address_space(3))) u32* las_p;
// async global->LDS, 16B per lane; lds dst is wave-uniform base + lane*16B
__device__ __forceinline__ void gld_lds16(const void* g, void* l) {
  __builtin_amdgcn_global_load_lds((gas_p)(unsigned long long)g,
                                   (las_p)(u32)(unsigned long long)l, 16, 0, 0);
}

// ---------- convert f32 -> bf16 (vectorized) ----------
__global__ __launch_bounds__(256) void cvt_f32_bf16(const float4* __restrict__ in,
                                                    uint2* __restrict__ out) {
  int i = blockIdx.x * 256 + threadIdx.x;
  float4 v = in[i];
  uint2 r;
  r.x = (u32)f2bf(v.x) | ((u32)f2bf(v.y) << 16);
  r.y = (u32)f2bf(v.z) | ((u32)f2bf(v.w) << 16);
  out[i] = r;
}

// ---------- transpose + convert: in[R][C] f32 -> out[C][R] bf16 ----------
__global__ __launch_bounds__(256) void transp_cvt(const float* __restrict__ in,
                                                  u16* __restrict__ out, int R, int C) {
  __shared__ float tile[32][33];
  int n0 = blockIdx.x * 32, k0 = blockIdx.y * 32;
  int tx = threadIdx.x, ty = threadIdx.y;   // block (32,8)
#pragma unroll
  for (int i = 0; i < 32; i += 8) tile[ty + i][tx] = in[(k0 + ty + i) * C + n0 + tx];
  __syncthreads();
#pragma unroll
  for (int i = 0; i < 32; i += 8) out[(n0 + ty + i) * R + k0 + tx] = f2bf(tile[tx][ty + i]);
}

// ---------- GEMM v3: 3-buffer rotation, counted vmcnt, 1 barrier/K-tile ----------
// C = A[M][K] @ Bt[N][K]^T. BM=256, BN=128, BK=64, 8 waves (512 thr, 4Mx2N).
// Schedule per K-tile t (buf=t%3): [vmcnt(6); s_barrier] then two kk-phases of
// {8 ds_read_b128 | 3 stage loads of tile t+2 -> buf (t+2)%3 | setprio 16 MFMA}.
// Safety: S(t+2) targets buf (t-1)%3 whose readers all passed this tile's
// barrier; vmcnt(6)+barrier certifies S(t) landed for ALL waves.
// MODE 0: QKV epilogue (RoPE on Q/K, V transposed). MODE 1: plain f32 store.
template<int MODE>
__global__ __launch_bounds__(512) void gemm_pipe3(
    const u16* __restrict__ A, const u16* __restrict__ Bt,
    int M, int N, int K,
    const float* __restrict__ cosb, const float* __restrict__ sinb,
    u16* __restrict__ Qb, u16* __restrict__ Kb, u16* __restrict__ Vt,
    float* __restrict__ outf) {
  constexpr int BM = 256, BN = 128;

  __shared__ u16 As[3][BM][64];           // 96 KB, rows 128B, swizzled via source
  __shared__ u16 Bs[3][BN][64];           // 48 KB

  const int tid = threadIdx.x;
  const int wv = tid >> 6, lane = tid & 63;
  const int c = lane & 15, g = lane >> 4;
  const int swz = (c & 7) << 4;           // byte-XOR for frag reads

  // XCD-aware bijective block swizzle (nwg % 8 == 0 for both instantiations)
  const int nwg = gridDim.x * gridDim.y;
  const int obid = blockIdx.y * gridDim.x + blockIdx.x;
  const int bid = (obid & 7) * (nwg >> 3) + (obid >> 3);
  const int m0 = (bid / gridDim.x) * BM;
  const int n0 = (bid % gridDim.x) * BN;

  const int wm = wv >> 1, wn = wv & 1;    // 4 x 2 wave grid, 64x64 per wave

  const int lr = lane >> 3;
  const int lc8 = ((lane & 7) ^ lr) * 8;  // pre-swizzled source col (elem)

  f32x4 acc[4][4] = {};
  const int NT = K >> 6;                  // K/64 tiles

  // stage tile t into buf: A 4 chunks/wave, B 2 chunks/wave (chunk=8rows, 1KB)
  auto STAGE_A = [&](int buf, int t, int i) {
    const int ch = wv * 4 + i;
    gld_lds16(A + (long)(m0 + ch * 8 + lr) * K + t * 64 + lc8, &As[buf][ch * 8][0]);
  };
  auto STAGE_B = [&](int buf, int t, int i) {
    const int ch = wv * 2 + i;
    gld_lds16(Bt + (long)(n0 + ch * 8 + lr) * K + t * 64 + lc8, &Bs[buf][ch * 8][0]);
  };
  auto STAGE_ALL = [&](int buf, int t) {
#pragma unroll
    for (int i = 0; i < 4; i++) STAGE_A(buf, t, i);
#pragma unroll
    for (int i = 0; i < 2; i++) STAGE_B(buf, t, i);
  };

  STAGE_ALL(0, 0);
  STAGE_ALL(1, 1);

  for (int t = 0; t < NT; ++t) {
    const int buf = t % 3;
    if (t < NT - 1) asm volatile("s_waitcnt vmcnt(6)" ::: "memory");
    else            asm volatile("s_waitcnt vmcnt(0)" ::: "memory");
    __builtin_amdgcn_s_barrier();
    __builtin_amdgcn_sched_barrier(0);
    const bool ds = (t + 2 < NT);
    const int sbuf = (t + 2) % 3;
    // ---- phase 0 (kk=0) ----
    {
      bf16x8 af[4], bfr[4];
#pragma unroll
      for (int i = 0; i < 4; i++)
        af[i] = ldb128(&As[buf][wm * 64 + i * 16 + c][((g * 16) ^ swz) >> 1]);
#pragma unroll
      for (int j = 0; j < 4; j++)
        bfr[j] = ldb128(&Bs[buf][wn * 64 + j * 16 + c][((g * 16) ^ swz) >> 1]);
      if (ds) { STAGE_A(sbuf, t + 2, 0); STAGE_A(sbuf, t + 2, 1); STAGE_B(sbuf, t + 2, 0); }
      __builtin_amdgcn_s_setprio(1);
#pragma unroll
      for (int i = 0; i < 4; i++)
#pragma unroll
        for (int j = 0; j < 4; j++)
          acc[i][j] = mfma16(af[i], bfr[j], acc[i][j]);
      __builtin_amdgcn_s_setprio(0);
    }
    // ---- phase 1 (kk=1) ----
    {
      bf16x8 af[4], bfr[4];
#pragma unroll
      for (int i = 0; i < 4; i++)
        af[i] = ldb128(&As[buf][wm * 64 + i * 16 + c][((64 + g * 16) ^ swz) >> 1]);
#pragma unroll
      for (int j = 0; j < 4; j++)
        bfr[j] = ldb128(&Bs[buf][wn * 64 + j * 16 + c][((64 + g * 16) ^ swz) >> 1]);
      if (ds) { STAGE_A(sbuf, t + 2, 2); STAGE_A(sbuf, t + 2, 3); STAGE_B(sbuf, t + 2, 1); }
      __builtin_amdgcn_s_setprio(1);
#pragma unroll
      for (int i = 0; i < 4; i++)
#pragma unroll
        for (int j = 0; j < 4; j++)
          acc[i][j] = mfma16(af[i], bfr[j], acc[i][j]);
      __builtin_amdgcn_s_setprio(0);
    }
  }

  // ---------- epilogue ----------
  // Q absorbs 1/sqrt(hd) * log2(e) so attention can use exp2 directly.
  const float q_scale = 0.12751743f;
#pragma unroll
  for (int i = 0; i < 4; i++) {
#pragma unroll
    for (int j = 0; j < 4; j++) {
      const int ncol = n0 + wn * 64 + j * 16 + c;
      if (MODE == 1) {
#pragma unroll
        for (int r = 0; r < 4; r++) {
          const int m = m0 + wm * 64 + i * 16 + g * 4 + r;
          outf[(long)m * N + ncol] = acc[i][j][r];
        }
        continue;
      }
      if (ncol < 2560) {                // Q or K: RoPE
#pragma unroll
        for (int r = 0; r < 4; r++) {
          const int m = m0 + wm * 64 + i * 16 + g * 4 + r;
          const int s = m & 2047;
          const int d = ncol & 127;
          float val = acc[i][j][r];
          float ct = cosb[s * 128 + d], st = sinb[s * 128 + d];
          float pr = __shfl_xor(val, 1, 64);
          float rot = (ncol & 1) ? pr : -pr;
          float rp = val * ct + rot * st;
          if (ncol < 2048) Qb[m * 2048 + ncol] = f2bf(rp * q_scale);
          else             Kb[m * 512 + (ncol - 2048)] = f2bf(rp);
        }
      } else {                          // V: store transposed Vt[bkvh*128+d][s]
        const int m_base = m0 + wm * 64 + i * 16 + g * 4;
        const int bb = m_base >> 11;
        const int srow = m_base & 2047; // contiguous over r
        uint2 pv;
        pv.x = pack2(acc[i][j][0], acc[i][j][1]);
        pv.y = pack2(acc[i][j][2], acc[i][j][3]);
        *(uint2*)&Vt[(bb * 512 + (ncol - 2560)) * 2048 + srow] = pv;
      }
    }
  }
}

// ---------- flash attention v3: 2 q-sets/wave, double-buffered K/V, exp2 ----------
// Block: 4 waves x 32 q-rows = 128 q. KV tile 64. K/V XOR-swizzled via source.
__global__ __launch_bounds__(256, 2) void attn_fwd(
    const u16* __restrict__ Qb, const u16* __restrict__ Kb,
    const u16* __restrict__ Vt, u16* __restrict__ attnb) {
  __shared__ u16 Ks[2][64 * 128];       // [key][d] swizzled, double-buffered
  __shared__ u16 Vs[2][128 * 64];       // [d][key] swizzled
  __shared__ u16 Pl[4][2][16 * 64];     // per-wave, per-set P [q][k] swizzled
  const int tid = threadIdx.x;
  const int wv = tid >> 6, lane = tid & 63;
  const int c = lane & 15, g = lane >> 4;
  const int qt = 15 - (int)blockIdx.x;  // heavy blocks first
  const int h = blockIdx.y, b = blockIdx.z;
  const int kvh = h >> 2;
  const int qbase = qt * 128 + wv * 32; // +set*16+c
  const int swz = (c & 7) << 4;

  // Q fragments for both sets (Q already scaled by log2e/sqrt(hd))
  bf16x8 qf0[4], qf1[4];
  {
    const u16* qp0 = Qb + ((b << 11) + qbase + c) * 2048 + h * 128 + g * 8;
#pragma unroll
    for (int dc = 0; dc < 4; dc++) qf0[dc] = ldb128(qp0 + dc * 32);
    const u16* qp1 = qp0 + 16 * 2048;
#pragma unroll
    for (int dc = 0; dc < 4; dc++) qf1[dc] = ldb128(qp1 + dc * 32);
  }

  f32x4 oacc0[8] = {}, oacc1[8] = {};
  float m0r = -1e30f, l0r = 0.f, m1r = -1e30f, l1r = 0.f;

  const int krow = wv * 16 + g;
  const int vrow = wv * 32 + (lane >> 3);
  const u16* Kg = Kb + kvh * 128;
  const u16* Vg = Vt + (b * 512 + kvh * 128) * 2048;
  const int NKV = 2 * qt + 2;

  auto STAGE = [&](int buf, int t) {
    const int k0 = t * 64;
#pragma unroll
    for (int i = 0; i < 4; i++) {
      const int r = krow + i * 4;
      gld_lds16(Kg + ((long)(b * 2048 + k0 + r)) * 512 + ((c ^ (r & 7)) * 8),
                &Ks[buf][(wv * 4 + i) * 512]);
    }
#pragma unroll
    for (int i = 0; i < 4; i++) {
      const int r = vrow + i * 8;
      gld_lds16(Vg + (long)r * 2048 + k0 + (((lane & 7) ^ (r & 7)) * 8),
                &Vs[buf][(wv * 4 + i) * 512]);
    }
  };

  STAGE(0, 0);
  for (int kt = 0; kt < NKV; kt++) {
    const int buf = kt & 1;
    const int k0 = kt * 64;
    if (kt + 1 < NKV) {
      STAGE(buf ^ 1, kt + 1);
      asm volatile("s_waitcnt vmcnt(8)" ::: "memory");
    } else {
      asm volatile("s_waitcnt vmcnt(0)" ::: "memory");
    }
    __builtin_amdgcn_s_barrier();
    __builtin_amdgcn_sched_barrier(0);

    // ---- S^T for both q-sets, sharing K-fragment reads ----
    f32x4 t0[4] = {}, t1[4] = {};
    __builtin_amdgcn_s_setprio(1);
#pragma unroll
    for (int kf = 0; kf < 4; kf++) {
#pragma unroll
      for (int dc = 0; dc < 4; dc++) {
        const bf16x8 kfr =
            ldb128(&Ks[buf][(kf * 16 + c) * 128 + (((dc * 64 + g * 16) ^ swz) >> 1)]);
        t0[kf] = mfma16(kfr, qf0[dc], t0[kf]);
        t1[kf] = mfma16(kfr, qf1[dc], t1[kf]);
      }
    }
    __builtin_amdgcn_s_setprio(0);
    if (kt >= NKV - 2) {                 // diagonal region: causal mask
      const int q0 = qbase + c, q1 = q0 + 16;
#pragma unroll
      for (int kf = 0; kf < 4; kf++)
#pragma unroll
        for (int r = 0; r < 4; r++) {
          const int key = k0 + kf * 16 + g * 4 + r;
          if (key > q0) t0[kf][r] = -1e30f;
          if (key > q1) t1[kf][r] = -1e30f;
        }
    }
    // ---- online softmax per set (exp2 domain, defer-max T13) ----
#pragma unroll
    for (int s = 0; s < 2; s++) {
      f32x4* t = s ? t1 : t0;
      float& mr = s ? m1r : m0r;
      float& lr_ = s ? l1r : l0r;
      f32x4* oa = s ? oacc1 : oacc0;
      float pmax = -1e30f;
#pragma unroll
      for (int kf = 0; kf < 4; kf++)
#pragma unroll
        for (int r = 0; r < 4; r++) pmax = fmaxf(pmax, t[kf][r]);
      pmax = fmaxf(pmax, __shfl_xor(pmax, 16, 64));
      pmax = fmaxf(pmax, __shfl_xor(pmax, 32, 64));
      if (__any(pmax - mr > 8.f)) {      // rescale only when max grew materially
        const float mnew = fmaxf(mr, pmax);
        const float scale = __builtin_amdgcn_exp2f(mr - mnew);
        lr_ *= scale;
#pragma unroll
        for (int df = 0; df < 8; df++) oa[df] *= scale;
        mr = mnew;
      }
      float psum = 0.f;
#pragma unroll
      for (int kf = 0; kf < 4; kf++) {
        float p0 = __builtin_amdgcn_exp2f(t[kf][0] - mr);
        float p1 = __builtin_amdgcn_exp2f(t[kf][1] - mr);
        float p2 = __builtin_amdgcn_exp2f(t[kf][2] - mr);
        float p3 = __builtin_amdgcn_exp2f(t[kf][3] - mr);
        psum += (p0 + p1) + (p2 + p3);
        u32* pw = (u32*)&Pl[wv][s][c * 64 + (((kf * 32 + g * 8) ^ swz) >> 1)];
        pw[0] = pack2(p0, p1);
        pw[1] = pack2(p2, p3);
      }
      psum += __shfl_xor(psum, 16, 64);
      psum += __shfl_xor(psum, 32, 64);
      lr_ += psum;
    }

    // ---- PV for both sets, sharing V-fragment reads ----
    const bf16x8 pa0 = ldb128(&Pl[wv][0][c * 64 + (((g * 16) ^ swz) >> 1)]);
    const bf16x8 pa1 = ldb128(&Pl[wv][0][c * 64 + (((64 + g * 16) ^ swz) >> 1)]);
    const bf16x8 pb0 = ldb128(&Pl[wv][1][c * 64 + (((g * 16) ^ swz) >> 1)]);
    const bf16x8 pb1 = ldb128(&Pl[wv][1][c * 64 + (((64 + g * 16) ^ swz) >> 1)]);
    __builtin_amdgcn_s_setprio(1);
#pragma unroll
    for (int df = 0; df < 8; df++) {
      const int vb = (df * 16 + c) * 64;
      const bf16x8 v0 = ldb128(&Vs[buf][vb + (((g * 16) ^ swz) >> 1)]);
      const bf16x8 v1 = ldb128(&Vs[buf][vb + (((64 + g * 16) ^ swz) >> 1)]);
      oacc0[df] = mfma16(v0, pa0, oacc0[df]);
      oacc0[df] = mfma16(v1, pa1, oacc0[df]);
      oacc1[df] = mfma16(v0, pb0, oacc1[df]);
      oacc1[df] = mfma16(v1, pb1, oacc1[df]);
    }
    __builtin_amdgcn_s_setprio(0);
    __builtin_amdgcn_sched_barrier(0);
    asm volatile("" ::: "memory");
    __builtin_amdgcn_s_barrier();
  }

  const float ri0 = 1.f / l0r, ri1 = 1.f / l1r;
  const long ob0 = ((long)(b << 11) + qbase + c) * 2048 + h * 128 + g * 4;
#pragma unroll
  for (int df = 0; df < 8; df++) {
    uint2 o0, o1;
    o0.x = pack2(oacc0[df][0] * ri0, oacc0[df][1] * ri0);
    o0.y = pack2(oacc0[df][2] * ri0, oacc0[df][3] * ri0);
    o1.x = pack2(oacc1[df][0] * ri1, oacc1[df][1] * ri1);
    o1.y = pack2(oacc1[df][2] * ri1, oacc1[df][3] * ri1);
    *(uint2*)&attnb[ob0 + df * 16] = o0;
    *(uint2*)&attnb[ob0 + 16 * 2048 + df * 16] = o1;
  }
}

// ---------- launch ----------
extern "C" void kernel_launch(void* const* d_in, const int* in_sizes, int n_in,
                              void* d_out, int out_size, void* d_ws, size_t ws_size,
                              hipStream_t stream) {
  const float* X    = (const float*)d_in[0];  // (2,2048,2048)
  const float* cosb = (const float*)d_in[1];  // (2048,128)
  const float* sinb = (const float*)d_in[2];
  const float* Wq   = (const float*)d_in[3];  // (2048,2048)
  const float* Wk   = (const float*)d_in[4];  // (2048,512)
  const float* Wv   = (const float*)d_in[5];
  const float* Wo   = (const float*)d_in[6];  // (2048,2048)

  char* ws = (char*)d_ws;
  u16* Xb    = (u16*)(ws);                       // 4096x2048 bf16 : 16 MB
  u16* Wt    = (u16*)(ws + 16777216);            // 3072x2048 bf16 : 12 MB (Wq^T|Wk^T|Wv^T)
  u16* Wot   = (u16*)(ws + 29360128);            // 2048x2048 bf16 : 8 MB
  u16* Qb    = (u16*)(ws + 37748736);            // 4096x2048 bf16 : 16 MB
  u16* Kb    = (u16*)(ws + 54525952);            // 4096x512  bf16 : 4 MB
  u16* Vt    = (u16*)(ws + 58720256);            // 1024x2048 bf16 : 4 MB
  u16* attnb = Xb;                               // alias: Xb dead after QKV GEMM

  // 1) convert hidden to bf16
  cvt_f32_bf16<<<dim3(8192), dim3(256), 0, stream>>>((const float4*)X, (uint2*)Xb);
  // 2) transpose+convert weights -> [N][K] bf16
  transp_cvt<<<dim3(64, 64), dim3(32, 8), 0, stream>>>(Wq, Wt, 2048, 2048);
  transp_cvt<<<dim3(16, 64), dim3(32, 8), 0, stream>>>(Wk, Wt + 2048 * 2048, 2048, 512);
  transp_cvt<<<dim3(16, 64), dim3(32, 8), 0, stream>>>(Wv, Wt + 2560 * 2048, 2048, 512);
  transp_cvt<<<dim3(64, 64), dim3(32, 8), 0, stream>>>(Wo, Wot, 2048, 2048);
  // 3) fused QKV GEMM + RoPE epilogue (256x128 tile, grid 24x16=384)
  gemm_pipe3<0><<<dim3(24, 16), dim3(512), 0, stream>>>(
      Xb, Wt, 4096, 3072, 2048, cosb, sinb, Qb, Kb, Vt, nullptr);
  // 4) causal GQA flash attention (128 q/block, 512 blocks, 2 blocks/CU)
  attn_fwd<<<dim3(16, 16, 2), dim3(256), 0, stream>>>(Qb, Kb, Vt, attnb);
  // 5) output GEMM -> f32 d_out (256x128 tile, grid 16x16=256)
  gemm_pipe3<1><<<dim3(16, 16), dim3(512), 0, stream>>>(
      attnb, Wot, 4096, 2048, 2048, nullptr, nullptr, nullptr, nullptr, nullptr,
      (float*)d_out);
}